// Round 10
// baseline (126.123 us; speedup 1.0000x reference)
//
#include <hip/hip_runtime.h>

// EdgeLoss: mean |sobel_mag(gray(pred)) - sobel_mag(gray(target))|
// Inputs: prediction [16,3,512,512] f32, target [16,3,512,512] f32. Output: scalar f32.
// R10: R9 streaming structure (no LDS, no barriers, no cross-lane ops,
// branchless clamped halo) with SR 8 -> 4: grid 1024 -> 2048 single-wave
// blocks = 8 waves/CU (2/SIMD) for latency hiding. Halo re-read rises to
// 1.5x but is L3-absorbed (101 MB < 256 MB Infinity Cache).

constexpr int B = 16;
constexpr int H = 512;
constexpr int W = 512;
constexpr int PLANE = H * W;
constexpr int SR = 4;                          // output rows per wave
constexpr int STRIPS_PER_IMG = H / SR;         // 128
constexpr int NBLOCKS = B * STRIPS_PER_IMG;    // 2048 single-wave blocks
constexpr float EPS = 1e-6f;

__device__ __forceinline__ float4 ldg4(const float* p) {
    return *reinterpret_cast<const float4*>(p);
}
__device__ __forceinline__ float grayf(float r, float g, float b) {
    return 0.299f * r + 0.587f * g + 0.114f * b;
}

struct RowDS { float D[8]; float S[8]; };

// Load one image row (8 own cols + 2 halo cols), return horizontal diff/smooth.
__device__ __forceinline__ RowDS load_row(
    const float* __restrict__ x0, const float* __restrict__ x1,
    const float* __restrict__ x2, int rowOff, int cM, int cL, int cR)
{
    const int offM = rowOff + cM;
    const int offL = rowOff + cL;
    const int offR = rowOff + cR;

    const float4 r0 = ldg4(x0 + offM), r1 = ldg4(x0 + offM + 4);
    const float4 g0 = ldg4(x1 + offM), g1 = ldg4(x1 + offM + 4);
    const float4 b0 = ldg4(x2 + offM), b1 = ldg4(x2 + offM + 4);
    const float lr = x0[offL], lg = x1[offL], lb = x2[offL];
    const float rr = x0[offR], rg = x1[offR], rb = x2[offR];

    float G[10];                       // gray at cols cM-1 .. cM+8
    G[0] = grayf(lr, lg, lb);
    G[1] = grayf(r0.x, g0.x, b0.x);
    G[2] = grayf(r0.y, g0.y, b0.y);
    G[3] = grayf(r0.z, g0.z, b0.z);
    G[4] = grayf(r0.w, g0.w, b0.w);
    G[5] = grayf(r1.x, g1.x, b1.x);
    G[6] = grayf(r1.y, g1.y, b1.y);
    G[7] = grayf(r1.z, g1.z, b1.z);
    G[8] = grayf(r1.w, g1.w, b1.w);
    G[9] = grayf(rr, rg, rb);

    RowDS o;
    #pragma unroll
    for (int c = 0; c < 8; ++c) {
        o.D[c] = G[c + 2] - G[c];
        o.S[c] = G[c] + 2.0f * G[c + 1] + G[c + 2];
    }
    return o;
}

__global__ __launch_bounds__(64, 2) void edge_loss_kernel(
    const float* __restrict__ pred,
    const float* __restrict__ targ,
    float* __restrict__ partial)
{
    const int lane = threadIdx.x;              // 0..63
    const int bid  = blockIdx.x;
    const int img  = bid >> 7;                 // / STRIPS_PER_IMG (128)
    const int vs   = bid & 127;
    const int r0   = vs * SR;
    const int cM   = 8 * lane;                 // own cols [cM, cM+8)
    const int cL   = max(cM - 1, 0);           // replicate-left
    const int cR   = min(cM + 8, W - 1);       // replicate-right

    const float* __restrict__ p0 = pred + (size_t)img * 3 * PLANE;
    const float* __restrict__ p1 = p0 + PLANE;
    const float* __restrict__ p2 = p0 + 2 * PLANE;
    const float* __restrict__ t0 = targ + (size_t)img * 3 * PLANE;
    const float* __restrict__ t1 = t0 + PLANE;
    const float* __restrict__ t2 = t0 + 2 * PLANE;

    // prologue: rows r0-1 (clamped) and r0
    const int rmOff = max(r0 - 1, 0) * W;
    RowDS pm = load_row(p0, p1, p2, rmOff, cM, cL, cR);
    RowDS tm = load_row(t0, t1, t2, rmOff, cM, cL, cR);
    RowDS pc = load_row(p0, p1, p2, r0 * W, cM, cL, cR);
    RowDS tc = load_row(t0, t1, t2, r0 * W, cM, cL, cR);

    float acc = 0.0f;
    #pragma unroll
    for (int r = 0; r < SR; ++r) {
        const int rpOff = min(r0 + r + 1, H - 1) * W;
        RowDS pp = load_row(p0, p1, p2, rpOff, cM, cL, cR);
        RowDS tp = load_row(t0, t1, t2, rpOff, cM, cL, cR);

        #pragma unroll
        for (int c = 0; c < 8; ++c) {
            const float gx = (pm.D[c] + 2.0f * pc.D[c] + pp.D[c]) * 0.125f;
            const float gy = (pp.S[c] - pm.S[c]) * 0.125f;
            const float pe = sqrtf(gx * gx + gy * gy + EPS);
            const float hx = (tm.D[c] + 2.0f * tc.D[c] + tp.D[c]) * 0.125f;
            const float hy = (tp.S[c] - tm.S[c]) * 0.125f;
            const float te = sqrtf(hx * hx + hy * hy + EPS);
            acc += fabsf(pe - te);
        }
        pm = pc; pc = pp;                      // static roll, no runtime idx
        tm = tc; tc = tp;
    }

    // per-wave reduction; single-wave block, no barriers
    #pragma unroll
    for (int off = 32; off > 0; off >>= 1)
        acc += __shfl_down(acc, off);

    if (lane == 0) partial[bid] = acc;
}

__global__ __launch_bounds__(256) void reduce_kernel(
    const float* __restrict__ partial,
    float* __restrict__ out)
{
    const int tid = threadIdx.x;
    float acc = 0.0f;
    #pragma unroll
    for (int i = 0; i < NBLOCKS / 256; ++i)    // 8 coalesced loads
        acc += partial[tid + i * 256];

    #pragma unroll
    for (int off = 32; off > 0; off >>= 1)
        acc += __shfl_down(acc, off);

    __shared__ float wsum[4];
    if ((tid & 63) == 0) wsum[tid >> 6] = acc;
    __syncthreads();

    if (tid == 0) {
        const float s = wsum[0] + wsum[1] + wsum[2] + wsum[3];
        out[0] = s * (1.0f / (float)((size_t)B * H * W));   // 2^-22, exact
    }
}

extern "C" void kernel_launch(void* const* d_in, const int* in_sizes, int n_in,
                              void* d_out, int out_size, void* d_ws, size_t ws_size,
                              hipStream_t stream) {
    const float* pred = (const float*)d_in[0];
    const float* targ = (const float*)d_in[1];
    float* out = (float*)d_out;
    float* partial = (float*)d_ws;             // 2048 floats = 8 KB scratch

    edge_loss_kernel<<<NBLOCKS, 64, 0, stream>>>(pred, targ, partial);
    reduce_kernel<<<1, 256, 0, stream>>>(partial, out);
}